// Round 12
// baseline (289.679 us; speedup 1.0000x reference)
//
#include <hip/hip_runtime.h>
#include <hip/hip_bf16.h>

#define NN   50000
#define EE   800000
#define DDIN 128
#define HH   3
#define FF   64
#define HF   192
#define NEG  0.2f
#define LOG2E 1.4426950408889634f

typedef __attribute__((ext_vector_type(8))) short bf16x8;
typedef __attribute__((ext_vector_type(4))) float f32x4;
typedef __attribute__((ext_vector_type(2))) float f32x2;

__device__ __forceinline__ ushort f2bu(float f){
  __hip_bfloat16 h = __float2bfloat16(f);
  return *reinterpret_cast<ushort*>(&h);
}
// pair-convert: uint holding 2 bf16 -> f32x2 (2 VALU ops)
__device__ __forceinline__ f32x2 cvt2(uint a){
  f32x2 r;
  r.x = __uint_as_float(a << 16);
  r.y = __uint_as_float(a & 0xFFFF0000u);
  return r;
}
// packed leaky_relu(f+d): v_pk_add + v_pk_mul + v_pk_max
__device__ __forceinline__ f32x2 lk2(f32x2 f, f32x2 d){
  f32x2 x = f + d;
  return __builtin_elementwise_max(x, x * NEG);
}

#define DPP_ADD(v, ctrl, rmask) \
  v += __int_as_float(__builtin_amdgcn_update_dpp(0, __float_as_int(v), ctrl, rmask, 0xf, true))
// 16-lane row sum via inclusive scan toward lane 15 (row_shr 1,2,4,8)
#define ROW_SUM(v) do{ \
  DPP_ADD(v, 0x111, 0xf); \
  DPP_ADD(v, 0x112, 0xf); \
  DPP_ADD(v, 0x114, 0xf); \
  DPP_ADD(v, 0x118, 0xf); \
}while(0)
__device__ __forceinline__ float swz_bcast15(float v){
  return __int_as_float(__builtin_amdgcn_ds_swizzle(__float_as_int(v), 0x01F0));
}
__device__ __forceinline__ float xadd16(float v){
  return v + __int_as_float(__builtin_amdgcn_ds_swizzle(__float_as_int(v), 0x401F));
}
__device__ __forceinline__ float xadd32(float v, int bpidx){
  return v + __int_as_float(__builtin_amdgcn_ds_bpermute(bpidx, __float_as_int(v)));
}

// ---------------- fused: out0 copy + feats->bf16 + dst-degree count ----------------
__global__ __launch_bounds__(256) void copy_convert_count(
    const float4* __restrict__ in, float4* __restrict__ out,
    ushort4* __restrict__ outb, int n4,
    const int* __restrict__ dst, int* __restrict__ counts){
  int i = blockIdx.x * 256 + threadIdx.x;
  if (i < n4){
    float4 v = in[i];
    out[i] = v;
    ushort4 o;
    o.x = f2bu(v.x); o.y = f2bu(v.y); o.z = f2bu(v.z); o.w = f2bu(v.w);
    outb[i] = o;
  }
  if (i < EE) atomicAdd(&counts[dst[i]], 1);
}

__global__ __launch_bounds__(1024) void scan_local(const int* __restrict__ counts,
                                                   int* __restrict__ row_ptr,
                                                   int* __restrict__ bsums, int n){
  __shared__ int wsum[16];
  int i = blockIdx.x * 1024 + (int)threadIdx.x;
  int lane = threadIdx.x & 63, wid = threadIdx.x >> 6;
  int v = (i < n) ? counts[i] : 0;
  int x = v;
  #pragma unroll
  for (int off = 1; off < 64; off <<= 1){
    int t = __shfl_up(x, off);
    if (lane >= off) x += t;
  }
  if (lane == 63) wsum[wid] = x;
  __syncthreads();
  if (wid == 0 && lane < 16){
    int y = wsum[lane];
    #pragma unroll
    for (int off = 1; off < 16; off <<= 1){
      int t = __shfl_up(y, off);
      if (lane >= off) y += t;
    }
    wsum[lane] = y;
  }
  __syncthreads();
  int incl = x + (wid ? wsum[wid - 1] : 0);
  if (i < n) row_ptr[i + 1] = incl;
  if (threadIdx.x == 1023) bsums[blockIdx.x] = incl;
}

__global__ __launch_bounds__(64) void scan_bsums(int* __restrict__ bsums, int nb){
  int lane = threadIdx.x;
  int v = (lane < nb) ? bsums[lane] : 0;
  int x = v;
  #pragma unroll
  for (int off = 1; off < 64; off <<= 1){
    int t = __shfl_up(x, off);
    if (lane >= off) x += t;
  }
  if (lane < nb) bsums[lane] = x - v;   // exclusive
}

__global__ __launch_bounds__(1024) void scan_add(int* __restrict__ row_ptr,
                                                 const int* __restrict__ bsums, int n){
  int i = blockIdx.x * 1024 + (int)threadIdx.x;
  if (i < n) row_ptr[i + 1] += bsums[blockIdx.x];
  if (i == 0) row_ptr[0] = 0;
}

__global__ __launch_bounds__(256) void scatter_kernel(const int* __restrict__ src,
                                                      const int* __restrict__ dst,
                                                      const int* __restrict__ row_ptr,
                                                      int* __restrict__ cursor,
                                                      int* __restrict__ srcs){
  int e = blockIdx.x * 256 + threadIdx.x;
  if (e >= EE) return;
  int d = dst[e];
  int pos = atomicAdd(&cursor[d], 1);
  srcs[row_ptr[d] + pos] = src[e];
}

// ---------------- build Wt for BOTH layers in one launch ----------------
__global__ __launch_bounds__(256) void build_wt2(
    const float* __restrict__ W1s, const float* __restrict__ W1d,
    const float* __restrict__ b1s, const float* __restrict__ b1d,
    const float* __restrict__ W2s, const float* __restrict__ W2d,
    const float* __restrict__ b2s, const float* __restrict__ b2d,
    ushort* __restrict__ Wt1, ushort* __restrict__ Wt2,
    float* __restrict__ bcat1, float* __restrict__ bcat2){
  int idx = blockIdx.x * 256 + threadIdx.x;
  if (idx < 384 * DDIN){
    int col = idx / DDIN, k = idx % DDIN;
    float v = (col < HF) ? W1s[(size_t)k * HF + col] : W1d[(size_t)k * HF + col - HF];
    Wt1[idx] = f2bu(v);
  } else if (idx < 384 * (DDIN + HF)){
    int j = idx - 384 * DDIN;
    int col = j / HF, k = j % HF;
    float v = (col < HF) ? W2s[(size_t)k * HF + col] : W2d[(size_t)k * HF + col - HF];
    Wt2[j] = f2bu(v);
  }
  if (idx < 384){
    bcat1[idx] = (idx < HF) ? b1s[idx] : b1d[idx - HF];
    bcat2[idx] = (idx < HF) ? b2s[idx] : b2d[idx - HF];
  }
}

// ---------------- persistent-B MFMA GEMM (R11-proven) ----------------
template<int K>
__global__ __launch_bounds__(512, 2) void gemm_persist(
    const ushort* __restrict__ A,
    const ushort* __restrict__ Wt,
    const float* __restrict__ bcat,
    ushort* __restrict__ fsb,
    ushort* __restrict__ fdb,
    int M, int nchunks, int stride){
  constexpr int RB  = K * 2;
  constexpr int CHB = 64 * RB;
  constexpr int NP  = CHB / 8192;
  constexpr int NKK = K / 32;
  __shared__ __align__(16) char lds[2][CHB];
  int tx = threadIdx.x;
  int w = tx >> 6, lane = tx & 63;
  int lr = lane & 15, lq = lane >> 4;

  bf16x8 bfr[3][NKK];
  float4 bv4[3];
  ushort* cb[3];
  #pragma unroll
  for (int ct = 0; ct < 3; ct++){
    int col0 = w * 48 + ct * 16;
    #pragma unroll
    for (int kk = 0; kk < NKK; kk++)
      bfr[ct][kk] = *(const bf16x8*)(Wt + (size_t)(col0 + lr) * K + kk * 32 + lq * 8);
    bv4[ct] = *(const float4*)(bcat + col0 + lq * 4);
    int colbase = col0 + lq * 4;
    cb[ct] = (w < 4) ? (fsb + colbase) : (fdb + colbase - HF);
  }

  int ldsw[NP];
  #pragma unroll
  for (int p = 0; p < NP; p++){
    int s = p * 8192 + tx * 16;
    int r = s / RB, cbyte = s % RB;
    ldsw[p] = r * RB + (cbyte ^ ((r & 7) << 4));
  }

  const char* Ab = (const char*)A;
  int c0 = blockIdx.x;
  if (c0 >= nchunks) return;
  uint4 stg[NP];
  #pragma unroll
  for (int p = 0; p < NP; p++)
    stg[p] = *(const uint4*)(Ab + (size_t)c0 * CHB + p * 8192 + tx * 16);

  int cur = 0;
  for (int c = c0; c < nchunks; c += stride, cur ^= 1){
    char* buf = lds[cur];
    #pragma unroll
    for (int p = 0; p < NP; p++)
      *(uint4*)(buf + ldsw[p]) = stg[p];
    __syncthreads();
    int nc = c + stride;
    if (nc < nchunks){
      #pragma unroll
      for (int p = 0; p < NP; p++)
        stg[p] = *(const uint4*)(Ab + (size_t)nc * CHB + p * 8192 + tx * 16);
    }
    f32x4 acc[4][3];
    #pragma unroll
    for (int rt = 0; rt < 4; rt++)
      #pragma unroll
      for (int ct = 0; ct < 3; ct++)
        acc[rt][ct] = (f32x4){0.f, 0.f, 0.f, 0.f};
    #pragma unroll
    for (int kk = 0; kk < NKK; kk++){
      bf16x8 afr[4];
      #pragma unroll
      for (int rt = 0; rt < 4; rt++){
        int r = rt * 16 + lr;
        int cbyte = kk * 64 + lq * 16;
        afr[rt] = *(const bf16x8*)(buf + r * RB + (cbyte ^ ((r & 7) << 4)));
      }
      #pragma unroll
      for (int rt = 0; rt < 4; rt++)
        #pragma unroll
        for (int ct = 0; ct < 3; ct++)
          acc[rt][ct] = __builtin_amdgcn_mfma_f32_16x16x32_bf16(bfr[ct][kk], afr[rt], acc[rt][ct], 0, 0, 0);
    }
    #pragma unroll
    for (int rt = 0; rt < 4; rt++){
      int row = c * 64 + rt * 16 + lr;
      if (row < M){
        #pragma unroll
        for (int ct = 0; ct < 3; ct++){
          ushort4 o;
          o.x = f2bu(acc[rt][ct][0] + bv4[ct].x);
          o.y = f2bu(acc[rt][ct][1] + bv4[ct].y);
          o.z = f2bu(acc[rt][ct][2] + bv4[ct].z);
          o.w = f2bu(acc[rt][ct][3] + bv4[ct].w);
          *(ushort4*)(cb[ct] + (size_t)row * HF) = o;
        }
      }
    }
  }
}

// ---------------- fused per-node, QUAD layout + packed-f32 math ----------------
// Same structure as R8's node_fused6 (proven 72us); inner math on f32x2 so
// clang emits v_pk_{add,mul,max,fma}_f32 -> ~27% fewer VALU instrs.
__global__ __launch_bounds__(256) void node_fused8(
    const ushort* __restrict__ fsb,
    const ushort* __restrict__ fdb,
    const int* __restrict__ row_ptr,
    const int* __restrict__ srcs,
    const float* __restrict__ attn,
    const float* __restrict__ bias,
    float* __restrict__ out,
    ushort* __restrict__ outb){
  int node = (blockIdx.x * 256 + (int)threadIdx.x) >> 6;
  int lane = threadIdx.x & 63;
  if (node >= NN) return;
  int q = lane >> 4;
  int k = lane & 15;
  int r0  = __builtin_amdgcn_readfirstlane(row_ptr[node]);
  int r1  = __builtin_amdgcn_readfirstlane(row_ptr[node + 1]);
  int deg = r1 - r0;
  int bp32 = ((lane ^ 32) << 2);

  const ushort* fdr = fdb + (size_t)node * HF + k * 4;
  uint2 fdu0 = *(const uint2*)(fdr);
  uint2 fdu1 = *(const uint2*)(fdr + 64);
  uint2 fdu2 = *(const uint2*)(fdr + 128);
  f32x2 fd2[6] = {cvt2(fdu0.x), cvt2(fdu0.y), cvt2(fdu1.x),
                  cvt2(fdu1.y), cvt2(fdu2.x), cvt2(fdu2.y)};
  const float* atp = attn + k * 4;
  float4 a0 = *(const float4*)(atp);
  float4 a1 = *(const float4*)(atp + 64);
  float4 a2 = *(const float4*)(atp + 128);
  f32x2 at2[6] = {(f32x2){a0.x, a0.y} * LOG2E, (f32x2){a0.z, a0.w} * LOG2E,
                  (f32x2){a1.x, a1.y} * LOG2E, (f32x2){a1.z, a1.w} * LOG2E,
                  (f32x2){a2.x, a2.y} * LOG2E, (f32x2){a2.z, a2.w} * LOG2E};

  float s0 = 0.f, s1 = 0.f, s2 = 0.f;
  f32x2 acc2[6];
  #pragma unroll
  for (int i = 0; i < 6; i++) acc2[i] = (f32x2){0.f, 0.f};

  if (deg > 0){
    uint2 cu0, cu1, cu2;
    {
      int ei = r0 + min(q, deg - 1);
      const ushort* p = fsb + (size_t)srcs[ei] * HF + k * 4;
      cu0 = *(const uint2*)(p);
      cu1 = *(const uint2*)(p + 64);
      cu2 = *(const uint2*)(p + 128);
    }
    for (int j = 0; j < deg; j += 4){
      f32x2 f0a = cvt2(cu0.x), f0b = cvt2(cu0.y);
      f32x2 f1a = cvt2(cu1.x), f1b = cvt2(cu1.y);
      f32x2 f2a = cvt2(cu2.x), f2b = cvt2(cu2.y);
      if (j + 4 < deg){
        int ei = r0 + min(j + 4 + q, deg - 1);
        const ushort* p = fsb + (size_t)srcs[ei] * HF + k * 4;
        cu0 = *(const uint2*)(p);
        cu1 = *(const uint2*)(p + 64);
        cu2 = *(const uint2*)(p + 128);
      }
      // packed leaky-dot: per head 2x (pk_add,pk_mul,pk_max,pk_fma)
      f32x2 p0v = lk2(f0a, fd2[0]) * at2[0] + lk2(f0b, fd2[1]) * at2[1];
      f32x2 p1v = lk2(f1a, fd2[2]) * at2[2] + lk2(f1b, fd2[3]) * at2[3];
      f32x2 p2v = lk2(f2a, fd2[4]) * at2[4] + lk2(f2b, fd2[5]) * at2[5];
      float p0 = p0v.x + p0v.y;
      float p1 = p1v.x + p1v.y;
      float p2 = p2v.x + p2v.y;
      ROW_SUM(p0); ROW_SUM(p1); ROW_SUM(p2);
      p0 = swz_bcast15(p0); p1 = swz_bcast15(p1); p2 = swz_bcast15(p2);
      bool valid = (j + q) < deg;
      float w0 = valid ? __builtin_amdgcn_exp2f(p0) : 0.f;
      float w1 = valid ? __builtin_amdgcn_exp2f(p1) : 0.f;
      float w2 = valid ? __builtin_amdgcn_exp2f(p2) : 0.f;
      s0 += w0; s1 += w1; s2 += w2;
      // packed weighted accumulate (6 pk_fma)
      acc2[0] += w0 * f0a; acc2[1] += w0 * f0b;
      acc2[2] += w1 * f1a; acc2[3] += w1 * f1b;
      acc2[4] += w2 * f2a; acc2[5] += w2 * f2b;
    }
  }

  // cross-quad combine (xor16 swizzle + xor32 bpermute), per 32-bit component
  float accs[12];
  #pragma unroll
  for (int i = 0; i < 6; i++){ accs[2 * i] = acc2[i].x; accs[2 * i + 1] = acc2[i].y; }
  #pragma unroll
  for (int i = 0; i < 12; i++){
    accs[i] = xadd16(accs[i]);
    accs[i] = xadd32(accs[i], bp32);
  }
  s0 = xadd16(s0); s0 = xadd32(s0, bp32);
  s1 = xadd16(s1); s1 = xadd32(s1, bp32);
  s2 = xadd16(s2); s2 = xadd32(s2, bp32);

  float i0 = deg ? 1.f / s0 : 0.f;
  float i1 = deg ? 1.f / s1 : 0.f;
  float i2 = deg ? 1.f / s2 : 0.f;

  if (q == 0){
    const float* bp = bias + k * 4;
    float4 b0 = *(const float4*)(bp);
    float4 b1 = *(const float4*)(bp + 64);
    float4 b2 = *(const float4*)(bp + 128);
    float v[12];
    v[0]  = tanhf(accs[0] * i0 + b0.x);  v[1]  = tanhf(accs[1] * i0 + b0.y);
    v[2]  = tanhf(accs[2] * i0 + b0.z);  v[3]  = tanhf(accs[3] * i0 + b0.w);
    v[4]  = tanhf(accs[4] * i1 + b1.x);  v[5]  = tanhf(accs[5] * i1 + b1.y);
    v[6]  = tanhf(accs[6] * i1 + b1.z);  v[7]  = tanhf(accs[7] * i1 + b1.w);
    v[8]  = tanhf(accs[8] * i2 + b2.x);  v[9]  = tanhf(accs[9] * i2 + b2.y);
    v[10] = tanhf(accs[10] * i2 + b2.z); v[11] = tanhf(accs[11] * i2 + b2.w);
    float* op = out + (size_t)node * HF + k * 4;
    *(float4*)(op)       = make_float4(v[0], v[1], v[2], v[3]);
    *(float4*)(op + 64)  = make_float4(v[4], v[5], v[6], v[7]);
    *(float4*)(op + 128) = make_float4(v[8], v[9], v[10], v[11]);
    if (outb){
      ushort* ob = outb + (size_t)node * HF + k * 4;
      ushort4 o0, o1, o2;
      o0.x = f2bu(v[0]); o0.y = f2bu(v[1]); o0.z = f2bu(v[2]); o0.w = f2bu(v[3]);
      o1.x = f2bu(v[4]); o1.y = f2bu(v[5]); o1.z = f2bu(v[6]); o1.w = f2bu(v[7]);
      o2.x = f2bu(v[8]); o2.y = f2bu(v[9]); o2.z = f2bu(v[10]); o2.w = f2bu(v[11]);
      *(ushort4*)(ob)       = o0;
      *(ushort4*)(ob + 64)  = o1;
      *(ushort4*)(ob + 128) = o2;
    }
  }
}

extern "C" void kernel_launch(void* const* d_in, const int* in_sizes, int n_in,
                              void* d_out, int out_size, void* d_ws, size_t ws_size,
                              hipStream_t stream) {
  const float* feats = (const float*)d_in[0];
  const int*   src   = (const int*)d_in[1];
  const int*   dst   = (const int*)d_in[2];
  const float* W1s = (const float*)d_in[3];  const float* b1s   = (const float*)d_in[4];
  const float* W1d = (const float*)d_in[5];  const float* b1d   = (const float*)d_in[6];
  const float* at1 = (const float*)d_in[7];  const float* bias1 = (const float*)d_in[8];
  const float* W2s = (const float*)d_in[9];  const float* b2s   = (const float*)d_in[10];
  const float* W2d = (const float*)d_in[11]; const float* b2d   = (const float*)d_in[12];
  const float* at2 = (const float*)d_in[13]; const float* bias2 = (const float*)d_in[14];

  float* out  = (float*)d_out;
  float* out1 = out  + (size_t)NN * DDIN;
  float* out2 = out1 + (size_t)NN * HF;

  char* ws = (char*)d_ws;
  ushort* fsb    = (ushort*)ws;                       ws += (size_t)NN * HF * 2;
  ushort* fdb    = (ushort*)ws;                       ws += (size_t)NN * HF * 2;
  ushort* out1b  = (ushort*)ws;                       ws += (size_t)NN * HF * 2;
  ushort* featsb = (ushort*)ws;                       ws += (size_t)NN * DDIN * 2;
  ushort* Wt1    = (ushort*)ws;                       ws += (size_t)384 * DDIN * 2;
  ushort* Wt2    = (ushort*)ws;                       ws += (size_t)384 * HF * 2;
  float*  bcat1  = (float*)ws;                        ws += 384 * 4;
  float*  bcat2  = (float*)ws;                        ws += 384 * 4;
  int*    counts = (int*)ws;                          ws += (size_t)NN * 4;
  int*    row_ptr= (int*)ws;                          ws += (size_t)(NN + 1) * 4;
  int*    srcs   = (int*)ws;                          ws += (size_t)EE * 4;
  int*    bsums  = (int*)ws;

  const int NB = (NN + 1023) / 1024;   // 49
  const int NCHUNK = (NN + 63) / 64;   // 782
  const int GEMM_GRID = 512;           // 2 blocks/CU

  const int N4 = NN * DDIN / 4;        // 1.6M

  // prep: out0 copy + bf16 convert + dst-degree count, then scan + scatter
  hipMemsetAsync(counts, 0, NN * sizeof(int), stream);
  copy_convert_count<<<(N4 + 255) / 256, 256, 0, stream>>>(
      (const float4*)feats, (float4*)out, (ushort4*)featsb, N4, dst, counts);
  scan_local<<<NB, 1024, 0, stream>>>(counts, row_ptr, bsums, NN);
  scan_bsums<<<1, 64, 0, stream>>>(bsums, NB);
  scan_add<<<NB, 1024, 0, stream>>>(row_ptr, bsums, NN);
  hipMemsetAsync(counts, 0, NN * sizeof(int), stream);
  scatter_kernel<<<(EE + 255) / 256, 256, 0, stream>>>(src, dst, row_ptr, counts, srcs);

  build_wt2<<<(384 * (DDIN + HF) + 255) / 256, 256, 0, stream>>>(
      W1s, W1d, b1s, b1d, W2s, W2d, b2s, b2d, Wt1, Wt2, bcat1, bcat2);

  int node_blocks = (NN + 3) / 4;

  // layer 1
  gemm_persist<DDIN><<<GEMM_GRID, 512, 0, stream>>>(featsb, Wt1, bcat1, fsb, fdb, NN, NCHUNK, GEMM_GRID);
  node_fused8<<<node_blocks, 256, 0, stream>>>(fsb, fdb, row_ptr, srcs, at1, bias1, out1, out1b);

  // layer 2
  gemm_persist<HF><<<GEMM_GRID, 512, 0, stream>>>(out1b, Wt2, bcat2, fsb, fdb, NN, NCHUNK, GEMM_GRID);
  node_fused8<<<node_blocks, 256, 0, stream>>>(fsb, fdb, row_ptr, srcs, at2, bias2, out2, nullptr);
}

// Round 14
// 248.903 us; speedup vs baseline: 1.1638x; 1.1638x over previous
//
#include <hip/hip_runtime.h>
#include <hip/hip_bf16.h>

#define NN   50000
#define EE   800000
#define DDIN 128
#define HH   3
#define FF   64
#define HF   192
#define NEG  0.2f
#define LOG2E 1.4426950408889634f

typedef __attribute__((ext_vector_type(8))) short bf16x8;
typedef __attribute__((ext_vector_type(4))) float f32x4;

__device__ __forceinline__ float b2f(ushort u){
  union { uint i; float f; } v; v.i = ((uint)u) << 16; return v.f;
}
__device__ __forceinline__ ushort f2bu(float f){
  __hip_bfloat16 h = __float2bfloat16(f);
  return *reinterpret_cast<ushort*>(&h);
}
__device__ __forceinline__ void us4_to_f(ushort4 u, float* f){
  f[0]=b2f(u.x); f[1]=b2f(u.y); f[2]=b2f(u.z); f[3]=b2f(u.w);
}

#define DPP_ADD(v, ctrl, rmask) \
  v += __int_as_float(__builtin_amdgcn_update_dpp(0, __float_as_int(v), ctrl, rmask, 0xf, true))
// 16-lane row sum via inclusive scan toward lane 15 (row_shr 1,2,4,8)
#define ROW_SUM(v) do{ \
  DPP_ADD(v, 0x111, 0xf); \
  DPP_ADD(v, 0x112, 0xf); \
  DPP_ADD(v, 0x114, 0xf); \
  DPP_ADD(v, 0x118, 0xf); \
}while(0)
__device__ __forceinline__ float swz_bcast15(float v){
  return __int_as_float(__builtin_amdgcn_ds_swizzle(__float_as_int(v), 0x01F0));
}
__device__ __forceinline__ float xadd16(float v){
  return v + __int_as_float(__builtin_amdgcn_ds_swizzle(__float_as_int(v), 0x401F));
}
__device__ __forceinline__ float xadd32(float v, int bpidx){
  return v + __int_as_float(__builtin_amdgcn_ds_bpermute(bpidx, __float_as_int(v)));
}

// ---------------- fused: out0 copy + feats->bf16 + dst-degree count (saves pos) ----------------
__global__ __launch_bounds__(256) void copy_convert_count(
    const float4* __restrict__ in, float4* __restrict__ out,
    ushort4* __restrict__ outb, int n4,
    const int* __restrict__ dst, int* __restrict__ counts,
    int* __restrict__ pos){
  int i = blockIdx.x * 256 + threadIdx.x;
  if (i < n4){
    float4 v = in[i];
    out[i] = v;
    ushort4 o;
    o.x = f2bu(v.x); o.y = f2bu(v.y); o.z = f2bu(v.z); o.w = f2bu(v.w);
    outb[i] = o;
  }
  if (i < EE) pos[i] = atomicAdd(&counts[dst[i]], 1);
}

__global__ __launch_bounds__(1024) void scan_local(const int* __restrict__ counts,
                                                   int* __restrict__ row_ptr,
                                                   int* __restrict__ bsums, int n){
  __shared__ int wsum[16];
  int i = blockIdx.x * 1024 + (int)threadIdx.x;
  int lane = threadIdx.x & 63, wid = threadIdx.x >> 6;
  int v = (i < n) ? counts[i] : 0;
  int x = v;
  #pragma unroll
  for (int off = 1; off < 64; off <<= 1){
    int t = __shfl_up(x, off);
    if (lane >= off) x += t;
  }
  if (lane == 63) wsum[wid] = x;
  __syncthreads();
  if (wid == 0 && lane < 16){
    int y = wsum[lane];
    #pragma unroll
    for (int off = 1; off < 16; off <<= 1){
      int t = __shfl_up(y, off);
      if (lane >= off) y += t;
    }
    wsum[lane] = y;
  }
  __syncthreads();
  int incl = x + (wid ? wsum[wid - 1] : 0);
  if (i < n) row_ptr[i + 1] = incl;
  if (threadIdx.x == 1023) bsums[blockIdx.x] = incl;
}

// merged: every wave redundantly scans the (<=64) block sums, then adds its
// block's exclusive offset to row_ptr (removes the separate scan_bsums launch)
__global__ __launch_bounds__(1024) void scan_add2(int* __restrict__ row_ptr,
                                                  const int* __restrict__ bsums,
                                                  int nb, int n){
  int lane = threadIdx.x & 63;
  int v = (lane < nb) ? bsums[lane] : 0;
  int x = v;
  #pragma unroll
  for (int off = 1; off < 64; off <<= 1){
    int t = __shfl_up(x, off);
    if (lane >= off) x += t;
  }
  int off_b = __shfl(x - v, (int)blockIdx.x);   // exclusive offset for this block
  int i = blockIdx.x * 1024 + (int)threadIdx.x;
  if (i < n) row_ptr[i + 1] += off_b;
  if (i == 0) row_ptr[0] = 0;
}

// atomic-free scatter using saved positions
__global__ __launch_bounds__(256) void scatter_pos(const int* __restrict__ src,
                                                   const int* __restrict__ dst,
                                                   const int* __restrict__ row_ptr,
                                                   const int* __restrict__ pos,
                                                   int* __restrict__ srcs){
  int e = blockIdx.x * 256 + threadIdx.x;
  if (e >= EE) return;
  srcs[row_ptr[dst[e]] + pos[e]] = src[e];
}

// ---------------- build Wt for BOTH layers in one launch ----------------
__global__ __launch_bounds__(256) void build_wt2(
    const float* __restrict__ W1s, const float* __restrict__ W1d,
    const float* __restrict__ b1s, const float* __restrict__ b1d,
    const float* __restrict__ W2s, const float* __restrict__ W2d,
    const float* __restrict__ b2s, const float* __restrict__ b2d,
    ushort* __restrict__ Wt1, ushort* __restrict__ Wt2,
    float* __restrict__ bcat1, float* __restrict__ bcat2){
  int idx = blockIdx.x * 256 + threadIdx.x;
  if (idx < 384 * DDIN){
    int col = idx / DDIN, k = idx % DDIN;
    float v = (col < HF) ? W1s[(size_t)k * HF + col] : W1d[(size_t)k * HF + col - HF];
    Wt1[idx] = f2bu(v);
  } else if (idx < 384 * (DDIN + HF)){
    int j = idx - 384 * DDIN;
    int col = j / HF, k = j % HF;
    float v = (col < HF) ? W2s[(size_t)k * HF + col] : W2d[(size_t)k * HF + col - HF];
    Wt2[j] = f2bu(v);
  }
  if (idx < 384){
    bcat1[idx] = (idx < HF) ? b1s[idx] : b1d[idx - HF];
    bcat2[idx] = (idx < HF) ? b2s[idx] : b2d[idx - HF];
  }
}

// ---------------- persistent-B MFMA GEMM with LDS-staged coalesced C stores ----------------
// MFMA phase as R11 (proven). Epilogue: C^T frags -> LDS (XOR-swizzled, 2-way
// conflict = free) -> fully-coalesced uint4 global stores. Fixes the 8B/384B-
// stride scattered stores (~8x HBM write amplification) of R9-R12.
// (R13 compile fix: no LDS pointer array — compute buffer offset in-loop.)
template<int K>
__global__ __launch_bounds__(512, 2) void gemm_persist(
    const ushort* __restrict__ A,
    const ushort* __restrict__ Wt,
    const float* __restrict__ bcat,
    ushort* __restrict__ fsb,
    ushort* __restrict__ fdb,
    int M, int nchunks, int stride){
  constexpr int RB  = K * 2;          // A row bytes
  constexpr int CHB = 64 * RB;        // A chunk bytes
  constexpr int NP  = CHB / 8192;     // A stage passes
  constexpr int NKK = K / 32;
  constexpr int CRB = 768;            // C row bytes (384 cols x 2B)
  __shared__ __align__(16) char lds[49152];   // 2x A buf (<=48KB) reused as 48KB C tile
  int tx = threadIdx.x;
  int w = tx >> 6, lane = tx & 63;
  int lr = lane & 15, lq = lane >> 4;

  bf16x8 bfr[3][NKK];
  float4 bv4[3];
  #pragma unroll
  for (int ct = 0; ct < 3; ct++){
    int col0 = w * 48 + ct * 16;
    #pragma unroll
    for (int kk = 0; kk < NKK; kk++)
      bfr[ct][kk] = *(const bf16x8*)(Wt + (size_t)(col0 + lr) * K + kk * 32 + lq * 8);
    bv4[ct] = *(const float4*)(bcat + col0 + lq * 4);
  }

  int ldsw[NP];
  #pragma unroll
  for (int p = 0; p < NP; p++){
    int s = p * 8192 + tx * 16;
    int r = s / RB, cbyte = s % RB;
    ldsw[p] = r * RB + (cbyte ^ ((r & 7) << 4));
  }

  const char* Ab = (const char*)A;
  int c0 = blockIdx.x;
  if (c0 >= nchunks) return;
  uint4 stg[NP];
  #pragma unroll
  for (int p = 0; p < NP; p++)
    stg[p] = *(const uint4*)(Ab + (size_t)c0 * CHB + p * 8192 + tx * 16);

  int cur = 0;
  for (int c = c0; c < nchunks; c += stride, cur ^= 1){
    int boff = cur ? CHB : 0;
    #pragma unroll
    for (int p = 0; p < NP; p++)
      *(uint4*)(lds + boff + ldsw[p]) = stg[p];
    __syncthreads();
    int nc = c + stride;
    if (nc < nchunks){
      #pragma unroll
      for (int p = 0; p < NP; p++)
        stg[p] = *(const uint4*)(Ab + (size_t)nc * CHB + p * 8192 + tx * 16);
    }
    f32x4 acc[4][3];
    #pragma unroll
    for (int rt = 0; rt < 4; rt++)
      #pragma unroll
      for (int ct = 0; ct < 3; ct++)
        acc[rt][ct] = (f32x4){0.f, 0.f, 0.f, 0.f};
    #pragma unroll
    for (int kk = 0; kk < NKK; kk++){
      bf16x8 afr[4];
      #pragma unroll
      for (int rt = 0; rt < 4; rt++){
        int r = rt * 16 + lr;
        int cbyte = kk * 64 + lq * 16;
        afr[rt] = *(const bf16x8*)(lds + boff + r * RB + (cbyte ^ ((r & 7) << 4)));
      }
      #pragma unroll
      for (int rt = 0; rt < 4; rt++)
        #pragma unroll
        for (int ct = 0; ct < 3; ct++)
          acc[rt][ct] = __builtin_amdgcn_mfma_f32_16x16x32_bf16(bfr[ct][kk], afr[rt], acc[rt][ct], 0, 0, 0);
    }
    // ---- C through LDS for coalesced stores ----
    __syncthreads();   // all A ds_reads done before overwriting LDS with C
    #pragma unroll
    for (int rt = 0; rt < 4; rt++){
      int r = rt * 16 + lr;
      int sw = (r & 7) << 4;
      #pragma unroll
      for (int ct = 0; ct < 3; ct++){
        ushort4 o;
        o.x = f2bu(acc[rt][ct][0] + bv4[ct].x);
        o.y = f2bu(acc[rt][ct][1] + bv4[ct].y);
        o.z = f2bu(acc[rt][ct][2] + bv4[ct].z);
        o.w = f2bu(acc[rt][ct][3] + bv4[ct].w);
        int cbyte = (w * 48 + ct * 16 + lq * 4) * 2;
        *(ushort4*)(lds + r * CRB + (cbyte ^ sw)) = o;
      }
    }
    __syncthreads();
    // coalesced: 512 thr x 6 x 16B = 48KB; contiguous 384B runs per row-half
    #pragma unroll
    for (int p = 0; p < 6; p++){
      int s = p * 8192 + tx * 16;
      int r = s / CRB, cbyte = s % CRB;
      int row = c * 64 + r;
      if (row < M){
        uint4 v = *(const uint4*)(lds + r * CRB + (cbyte ^ ((r & 7) << 4)));
        char* dstp = (cbyte < 384) ? ((char*)fsb + (size_t)row * 384 + cbyte)
                                   : ((char*)fdb + (size_t)row * 384 + cbyte - 384);
        *(uint4*)dstp = v;
      }
    }
    __syncthreads();   // C reads done before next iteration's A stage
  }
}

// ---------------- fused per-node, QUAD layout: 4 edges/iter (R8/R11-proven) ----------------
__global__ __launch_bounds__(256) void node_fused6(
    const ushort* __restrict__ fsb,
    const ushort* __restrict__ fdb,
    const int* __restrict__ row_ptr,
    const int* __restrict__ srcs,
    const float* __restrict__ attn,
    const float* __restrict__ bias,
    float* __restrict__ out,
    ushort* __restrict__ outb){
  int node = (blockIdx.x * 256 + (int)threadIdx.x) >> 6;
  int lane = threadIdx.x & 63;
  if (node >= NN) return;
  int q = lane >> 4;
  int k = lane & 15;
  int r0  = __builtin_amdgcn_readfirstlane(row_ptr[node]);
  int r1  = __builtin_amdgcn_readfirstlane(row_ptr[node + 1]);
  int deg = r1 - r0;
  int bp32 = ((lane ^ 32) << 2);

  const ushort* fdr = fdb + (size_t)node * HF + k * 4;
  float fd[12];
  us4_to_f(*(const ushort4*)(fdr),       fd);
  us4_to_f(*(const ushort4*)(fdr + 64),  fd + 4);
  us4_to_f(*(const ushort4*)(fdr + 128), fd + 8);
  const float* atp = attn + k * 4;
  float4 av0 = *(const float4*)(atp);
  float4 av1 = *(const float4*)(atp + 64);
  float4 av2 = *(const float4*)(atp + 128);
  float at[12] = {av0.x*LOG2E, av0.y*LOG2E, av0.z*LOG2E, av0.w*LOG2E,
                  av1.x*LOG2E, av1.y*LOG2E, av1.z*LOG2E, av1.w*LOG2E,
                  av2.x*LOG2E, av2.y*LOG2E, av2.z*LOG2E, av2.w*LOG2E};

  float s0 = 0.f, s1 = 0.f, s2 = 0.f;
  float acc[12];
  #pragma unroll
  for (int i = 0; i < 12; i++) acc[i] = 0.f;

  if (deg > 0){
    ushort4 cu0, cu1, cu2;
    {
      int ei = r0 + min(q, deg - 1);
      const ushort* p = fsb + (size_t)srcs[ei] * HF + k * 4;
      cu0 = *(const ushort4*)(p);
      cu1 = *(const ushort4*)(p + 64);
      cu2 = *(const ushort4*)(p + 128);
    }
    for (int j = 0; j < deg; j += 4){
      ushort4 nu0 = cu0, nu1 = cu1, nu2 = cu2;
      if (j + 4 < deg){
        int ei = r0 + min(j + 4 + q, deg - 1);
        const ushort* p = fsb + (size_t)srcs[ei] * HF + k * 4;
        nu0 = *(const ushort4*)(p);
        nu1 = *(const ushort4*)(p + 64);
        nu2 = *(const ushort4*)(p + 128);
      }
      float f[12];
      us4_to_f(cu0, f); us4_to_f(cu1, f + 4); us4_to_f(cu2, f + 8);
      float p0 = 0.f, p1 = 0.f, p2 = 0.f;
      #pragma unroll
      for (int i = 0; i < 4; i++){
        float x0 = f[i]     + fd[i];     x0 = fmaxf(x0, NEG * x0); p0 = fmaf(x0, at[i],     p0);
        float x1 = f[4 + i] + fd[4 + i]; x1 = fmaxf(x1, NEG * x1); p1 = fmaf(x1, at[4 + i], p1);
        float x2 = f[8 + i] + fd[8 + i]; x2 = fmaxf(x2, NEG * x2); p2 = fmaf(x2, at[8 + i], p2);
      }
      ROW_SUM(p0); ROW_SUM(p1); ROW_SUM(p2);
      p0 = swz_bcast15(p0); p1 = swz_bcast15(p1); p2 = swz_bcast15(p2);
      bool valid = (j + q) < deg;
      float w0 = valid ? __builtin_amdgcn_exp2f(p0) : 0.f;
      float w1 = valid ? __builtin_amdgcn_exp2f(p1) : 0.f;
      float w2 = valid ? __builtin_amdgcn_exp2f(p2) : 0.f;
      s0 += w0; s1 += w1; s2 += w2;
      #pragma unroll
      for (int i = 0; i < 4; i++){
        acc[i]     = fmaf(w0, f[i],     acc[i]);
        acc[4 + i] = fmaf(w1, f[4 + i], acc[4 + i]);
        acc[8 + i] = fmaf(w2, f[8 + i], acc[8 + i]);
      }
      cu0 = nu0; cu1 = nu1; cu2 = nu2;
    }
  }

  #pragma unroll
  for (int i = 0; i < 12; i++){
    acc[i] = xadd16(acc[i]);
    acc[i] = xadd32(acc[i], bp32);
  }
  s0 = xadd16(s0); s0 = xadd32(s0, bp32);
  s1 = xadd16(s1); s1 = xadd32(s1, bp32);
  s2 = xadd16(s2); s2 = xadd32(s2, bp32);

  float i0 = deg ? 1.f / s0 : 0.f;
  float i1 = deg ? 1.f / s1 : 0.f;
  float i2 = deg ? 1.f / s2 : 0.f;

  if (q == 0){
    const float* bp = bias + k * 4;
    float4 b0 = *(const float4*)(bp);
    float4 b1 = *(const float4*)(bp + 64);
    float4 b2 = *(const float4*)(bp + 128);
    float v[12];
    v[0]  = tanhf(acc[0] * i0 + b0.x);  v[1]  = tanhf(acc[1] * i0 + b0.y);
    v[2]  = tanhf(acc[2] * i0 + b0.z);  v[3]  = tanhf(acc[3] * i0 + b0.w);
    v[4]  = tanhf(acc[4] * i1 + b1.x);  v[5]  = tanhf(acc[5] * i1 + b1.y);
    v[6]  = tanhf(acc[6] * i1 + b1.z);  v[7]  = tanhf(acc[7] * i1 + b1.w);
    v[8]  = tanhf(acc[8] * i2 + b2.x);  v[9]  = tanhf(acc[9] * i2 + b2.y);
    v[10] = tanhf(acc[10] * i2 + b2.z); v[11] = tanhf(acc[11] * i2 + b2.w);
    float* op = out + (size_t)node * HF + k * 4;
    *(float4*)(op)       = make_float4(v[0], v[1], v[2], v[3]);
    *(float4*)(op + 64)  = make_float4(v[4], v[5], v[6], v[7]);
    *(float4*)(op + 128) = make_float4(v[8], v[9], v[10], v[11]);
    if (outb){
      ushort* ob = outb + (size_t)node * HF + k * 4;
      ushort4 o0, o1, o2;
      o0.x = f2bu(v[0]); o0.y = f2bu(v[1]); o0.z = f2bu(v[2]); o0.w = f2bu(v[3]);
      o1.x = f2bu(v[4]); o1.y = f2bu(v[5]); o1.z = f2bu(v[6]); o1.w = f2bu(v[7]);
      o2.x = f2bu(v[8]); o2.y = f2bu(v[9]); o2.z = f2bu(v[10]); o2.w = f2bu(v[11]);
      *(ushort4*)(ob)       = o0;
      *(ushort4*)(ob + 64)  = o1;
      *(ushort4*)(ob + 128) = o2;
    }
  }
}

extern "C" void kernel_launch(void* const* d_in, const int* in_sizes, int n_in,
                              void* d_out, int out_size, void* d_ws, size_t ws_size,
                              hipStream_t stream) {
  const float* feats = (const float*)d_in[0];
  const int*   src   = (const int*)d_in[1];
  const int*   dst   = (const int*)d_in[2];
  const float* W1s = (const float*)d_in[3];  const float* b1s   = (const float*)d_in[4];
  const float* W1d = (const float*)d_in[5];  const float* b1d   = (const float*)d_in[6];
  const float* at1 = (const float*)d_in[7];  const float* bias1 = (const float*)d_in[8];
  const float* W2s = (const float*)d_in[9];  const float* b2s   = (const float*)d_in[10];
  const float* W2d = (const float*)d_in[11]; const float* b2d   = (const float*)d_in[12];
  const float* at2 = (const float*)d_in[13]; const float* bias2 = (const float*)d_in[14];

  float* out  = (float*)d_out;
  float* out1 = out  + (size_t)NN * DDIN;
  float* out2 = out1 + (size_t)NN * HF;

  char* ws = (char*)d_ws;
  ushort* fsb    = (ushort*)ws;                       ws += (size_t)NN * HF * 2;
  ushort* fdb    = (ushort*)ws;                       ws += (size_t)NN * HF * 2;
  ushort* out1b  = (ushort*)ws;                       ws += (size_t)NN * HF * 2;
  ushort* featsb = (ushort*)ws;                       ws += (size_t)NN * DDIN * 2;
  ushort* Wt1    = (ushort*)ws;                       ws += (size_t)384 * DDIN * 2;
  ushort* Wt2    = (ushort*)ws;                       ws += (size_t)384 * HF * 2;
  float*  bcat1  = (float*)ws;                        ws += 384 * 4;
  float*  bcat2  = (float*)ws;                        ws += 384 * 4;
  int*    counts = (int*)ws;                          ws += (size_t)NN * 4;
  int*    row_ptr= (int*)ws;                          ws += (size_t)(NN + 1) * 4;
  int*    srcs   = (int*)ws;                          ws += (size_t)EE * 4;
  int*    pos    = (int*)ws;                          ws += (size_t)EE * 4;
  int*    bsums  = (int*)ws;

  const int NB = (NN + 1023) / 1024;   // 49
  const int NCHUNK = (NN + 63) / 64;   // 782
  const int GEMM_GRID = 512;           // 2 blocks/CU

  const int N4 = NN * DDIN / 4;        // 1.6M

  // prep: out0 copy + bf16 convert + dst-degree count (+pos), scan, scatter
  (void)hipMemsetAsync(counts, 0, NN * sizeof(int), stream);
  copy_convert_count<<<(N4 + 255) / 256, 256, 0, stream>>>(
      (const float4*)feats, (float4*)out, (ushort4*)featsb, N4, dst, counts, pos);
  scan_local<<<NB, 1024, 0, stream>>>(counts, row_ptr, bsums, NN);
  scan_add2<<<NB, 1024, 0, stream>>>(row_ptr, bsums, NB, NN);
  scatter_pos<<<(EE + 255) / 256, 256, 0, stream>>>(src, dst, row_ptr, pos, srcs);

  build_wt2<<<(384 * (DDIN + HF) + 255) / 256, 256, 0, stream>>>(
      W1s, W1d, b1s, b1d, W2s, W2d, b2s, b2d, Wt1, Wt2, bcat1, bcat2);

  int node_blocks = (NN + 3) / 4;

  // layer 1
  gemm_persist<DDIN><<<GEMM_GRID, 512, 0, stream>>>(featsb, Wt1, bcat1, fsb, fdb, NN, NCHUNK, GEMM_GRID);
  node_fused6<<<node_blocks, 256, 0, stream>>>(fsb, fdb, row_ptr, srcs, at1, bias1, out1, out1b);

  // layer 2
  gemm_persist<HF><<<GEMM_GRID, 512, 0, stream>>>(out1b, Wt2, bcat2, fsb, fdb, NN, NCHUNK, GEMM_GRID);
  node_fused6<<<node_blocks, 256, 0, stream>>>(fsb, fdb, row_ptr, srcs, at2, bias2, out2, nullptr);
}